// Round 7
// baseline (64.306 us; speedup 1.0000x reference)
//
#include <hip/hip_runtime.h>

#define A_DIM 1024
#define B_DIM 1024

typedef __attribute__((ext_vector_type(8))) short bfrag8;
typedef __attribute__((ext_vector_type(4))) float facc4;
typedef const __attribute__((address_space(1))) unsigned GasPtr;
typedef __attribute__((address_space(3))) unsigned LdsPtr;

__device__ __forceinline__ unsigned short f2bf(float f) {
    unsigned u = __float_as_uint(f);
    u = (u + 0x7FFFu + ((u >> 16) & 1u)) >> 16;
    return (unsigned short)u;
}
__device__ __forceinline__ unsigned cvtpk(float lo, float hi) {
    unsigned r;
    asm("v_cvt_pk_bf16_f32 %0, %1, %2" : "=v"(r) : "v"(lo), "v"(hi));
    return r;
}

// ---------------------------------------------------------------------------
// Kernel 1: ha[a][d] = b1e[d] + sum_k nodes_a[a][k] * Wa[k][d]
//           hb[b][d] =          sum_k nodes_b[b][k] * Wb[k][d]
// ---------------------------------------------------------------------------
__global__ __launch_bounds__(256) void prep_kernel(
    const float* __restrict__ na, const float* __restrict__ nb,
    const float* __restrict__ W1e, const float* __restrict__ b1e,
    float* __restrict__ ha, float* __restrict__ hb)
{
    int idx = blockIdx.x * 256 + threadIdx.x;   // 0..32767
    int half = idx >> 14;                       // 0 = a-side, 1 = b-side
    int r = (idx >> 4) & 1023;
    int d = idx & 15;
    const float* x = (half ? nb : na) + r * 32;
    const float* W = W1e + (half ? 64 * 16 : 32 * 16) + d;
    float acc = half ? 0.f : b1e[d];
    #pragma unroll
    for (int k = 0; k < 32; ++k) acc += x[k] * W[k * 16];
    (half ? hb : ha)[r * 16 + d] = acc;
}

// ---------------------------------------------------------------------------
// Kernel 2: fused edge MLP via MFMA. E staged through LDS with
// global_load_lds (async DMA, no receive VGPRs) into a WAVE-PRIVATE double
// buffer, counted s_waitcnt vmcnt(N) (never 0 mid-pipeline), no barriers in
// the main pipeline. LDS slots XOR-swizzled via pre-swizzled GLOBAL source
// addresses (DMA dest must be linear) -> ds_read_b128 is 2-way = free.
// Block = 512 threads = 8 waves, grid (16 bg, 64 at) = 1024 blocks,
// LDS 64KB -> 2 blocks/CU. Wave owns rows r0,r0+1; 4 half-row steps of 4KB.
// vmcnt issue-order math (per wave; 4 DMA/stage, 2 stores/step, pinned by
// sched_barrier): waits = {4, 6, 8, 4}.
// C/D layout: col = lane&15 (edge), row = (lane>>4)*4 + reg (d).
// ---------------------------------------------------------------------------
__global__ __launch_bounds__(512, 2) void edge_kernel(
    const float* __restrict__ E, const float* __restrict__ W1e,
    const float* __restrict__ W2e, const float* __restrict__ b2e,
    const float* __restrict__ ha, const float* __restrict__ hb,
    float* __restrict__ el_out, float* __restrict__ suma_p,
    float* __restrict__ sumb_p)
{
    __shared__ __align__(16) float stg[8 * 2048];   // 64KB: 8 waves x 2 x 4KB

    const int tid  = threadIdx.x;
    const int lane = tid & 63;
    const int w    = tid >> 6;          // 0..7
    const int n    = lane & 15;         // edge-in-tile / weight d-col
    const int g    = lane >> 4;         // 0..3  k-chunk / d-row group
    const int bg   = blockIdx.x;        // 0..15
    const int at   = blockIdx.y;        // 0..63
    const int bbase = bg * 64;
    const int r0   = at * 16 + w * 2;

    // ---- fragment gathers FIRST (their compiler waits must not drain DMA) --
    bfrag8 w1f, w2f;
    #pragma unroll
    for (int t = 0; t < 8; ++t) {
        w1f[t] = (short)f2bf(W1e[(g * 8 + t) * 16 + n]);
        w2f[t] = (g < 2) ? (short)f2bf(W2e[(g * 8 + t) * 16 + n]) : (short)0;
    }
    facc4 b2f = *(const facc4*)&b2e[g * 4];
    facc4 hbF[4];
    #pragma unroll
    for (int mt = 0; mt < 4; ++mt)
        hbF[mt] = *(const facc4*)&hb[(bbase + mt * 16 + n) * 16 + g * 4];
    facc4 haF[2];
    #pragma unroll
    for (int i = 0; i < 2; ++i)
        haF[i] = *(const facc4*)&ha[(r0 + i) * 16 + g * 4];
    __builtin_amdgcn_sched_barrier(0);

    // ---- staging geometry ----
    // tile = 32 edges x 32 k f32 (4KB). LDS row e (128B) slot s' holds global
    // slot s'^(e&7). DMA instruction t covers rows 8t..8t+7 linearly in LDS;
    // per-lane global source pre-applies the swizzle.
    float* lbuf = stg + w * 2048;
    const int gswf = ((lane >> 3) * 32) + (((lane & 7) ^ ((lane >> 3) & 7)) * 4);
    const int xm   = n & 7;
    const int rdA0 = n * 32 + (((g * 2) ^ xm) * 4);          // row n,  k 8g..8g+3
    const int rdA1 = n * 32 + ((((g * 2) | 1) ^ xm) * 4);    // row n,  k 8g+4..
    const int rdB0 = rdA0 + 512;                             // row n+16
    const int rdB1 = rdA1 + 512;

#define STAGE(BUF, A, H)                                                       \
    {                                                                          \
        const float* tb_ = E + ((size_t)(A) * B_DIM + bbase + (H) * 32) * 32   \
                             + gswf;                                           \
        float* lb_ = lbuf + (BUF) * 1024;                                      \
        _Pragma("unroll")                                                      \
        for (int t_ = 0; t_ < 4; ++t_)                                         \
            __builtin_amdgcn_global_load_lds((GasPtr*)(tb_ + t_ * 256),        \
                                             (LdsPtr*)(lb_ + t_ * 256),        \
                                             16, 0, 0);                        \
        __builtin_amdgcn_sched_barrier(0);                                     \
    }

#define PVTILE(V0, V1, MT, A, RI)                                              \
    {                                                                          \
        union { unsigned u[4]; bfrag8 s; } ef_;                                \
        ef_.u[0] = cvtpk(V0.x, V0.y); ef_.u[1] = cvtpk(V0.z, V0.w);            \
        ef_.u[2] = cvtpk(V1.x, V1.y); ef_.u[3] = cvtpk(V1.z, V1.w);            \
        facc4 h_ = __builtin_amdgcn_mfma_f32_16x16x32_bf16(                    \
            w1f, ef_.s, haF[RI] + hbF[MT], 0, 0, 0);                           \
        h_.x = fmaxf(h_.x, 0.f); h_.y = fmaxf(h_.y, 0.f);                      \
        h_.z = fmaxf(h_.z, 0.f); h_.w = fmaxf(h_.w, 0.f);                      \
        const int sl_ = (n + g * 32) & 63;                                     \
        const int sh_ = (n + g * 32 + 16) & 63;                                \
        float v0_ = __shfl(h_.x, sl_), v1_ = __shfl(h_.y, sl_);                \
        float v2_ = __shfl(h_.z, sl_), v3_ = __shfl(h_.w, sl_);                \
        float u0_ = __shfl(h_.x, sh_), u1_ = __shfl(h_.y, sh_);                \
        float u2_ = __shfl(h_.z, sh_), u3_ = __shfl(h_.w, sh_);                \
        union { unsigned u[4]; bfrag8 s; } bb_;                                \
        bb_.u[0] = cvtpk(v0_, v1_); bb_.u[1] = cvtpk(v2_, v3_);                \
        bb_.u[2] = cvtpk(u0_, u1_); bb_.u[3] = cvtpk(u2_, u3_);                \
        facc4 e_ = __builtin_amdgcn_mfma_f32_16x16x32_bf16(                    \
            w2f, bb_.s, b2f, 0, 0, 0);                                         \
        e_.x = fmaxf(e_.x, 0.f); e_.y = fmaxf(e_.y, 0.f);                      \
        e_.z = fmaxf(e_.z, 0.f); e_.w = fmaxf(e_.w, 0.f);                      \
        facc4* op_ = (facc4*)&el_out[((size_t)(A) * B_DIM + bbase              \
                                      + (MT) * 16 + n) * 16 + g * 4];          \
        __builtin_nontemporal_store(e_, op_);                                  \
        sumbA[MT] += e_;                                                       \
        ssum += e_;                                                            \
    }

#define STEP(BUF, A, RI, H, VM, DOSTAGE, NA, NH, SUMATGT, FH)                  \
    {                                                                          \
        asm volatile("s_waitcnt vmcnt(" #VM ")" ::: "memory");                 \
        __builtin_amdgcn_sched_barrier(0);                                     \
        float* lb_ = lbuf + (BUF) * 1024;                                      \
        facc4 vA0 = *(facc4*)(lb_ + rdA0);                                     \
        facc4 vA1 = *(facc4*)(lb_ + rdA1);                                     \
        facc4 vB0 = *(facc4*)(lb_ + rdB0);                                     \
        facc4 vB1 = *(facc4*)(lb_ + rdB1);                                     \
        asm volatile("s_waitcnt lgkmcnt(0)" ::: "memory");                     \
        __builtin_amdgcn_sched_barrier(0);                                     \
        if (DOSTAGE) { STAGE(BUF, NA, NH) }                                    \
        if (FH) ssum = facc4{0.f, 0.f, 0.f, 0.f};                              \
        PVTILE(vA0, vA1, (2 * (H)),     A, RI)                                 \
        PVTILE(vB0, vB1, (2 * (H) + 1), A, RI)                                 \
        if (!(FH)) {                                                           \
            _Pragma("unroll")                                                  \
            for (int m_ = 1; m_ <= 8; m_ <<= 1) {                              \
                ssum.x += __shfl_xor(ssum.x, m_);                              \
                ssum.y += __shfl_xor(ssum.y, m_);                              \
                ssum.z += __shfl_xor(ssum.z, m_);                              \
                ssum.w += __shfl_xor(ssum.w, m_);                              \
            }                                                                  \
            SUMATGT = ssum;                                                    \
        }                                                                      \
    }

    facc4 sumbA[4];
    #pragma unroll
    for (int mt = 0; mt < 4; ++mt) sumbA[mt] = facc4{0.f, 0.f, 0.f, 0.f};
    facc4 ssum  = facc4{0.f, 0.f, 0.f, 0.f};
    facc4 suma0 = facc4{0.f, 0.f, 0.f, 0.f};
    facc4 suma1 = facc4{0.f, 0.f, 0.f, 0.f};

    // prologue: both buffers of row r0 in flight
    STAGE(0, r0, 0)
    STAGE(1, r0, 1)
    // pipeline (issue order per wave: A B | s0: C W0 | s1: D W1 | s2: W2 | s3: W3)
    STEP(0, r0,     0, 0, 4, 1, r0 + 1, 0, suma0, 1)
    STEP(1, r0,     0, 1, 6, 1, r0 + 1, 1, suma0, 0)
    STEP(0, r0 + 1, 1, 0, 8, 0, 0,      0, suma1, 1)
    STEP(1, r0 + 1, 1, 1, 4, 0, 0,      0, suma1, 0)

#undef STAGE
#undef PVTILE
#undef STEP

    if (n == 0) {
        *(facc4*)&suma_p[((size_t)bg * A_DIM + r0)     * 16 + g * 4] = suma0;
        *(facc4*)&suma_p[((size_t)bg * A_DIM + r0 + 1) * 16 + g * 4] = suma1;
    }

    // ---- combine sumb across 8 waves (reuse staging LDS, 32KB) ----
    __syncthreads();
    #pragma unroll
    for (int mt = 0; mt < 4; ++mt)
        ((facc4*)stg)[(w * 64 + mt * 16 + n) * 4 + g] = sumbA[mt];
    __syncthreads();
    if (tid < 256) {
        const int bl = tid >> 2, q = tid & 3;
        facc4 s = facc4{0.f, 0.f, 0.f, 0.f};
        #pragma unroll
        for (int ww = 0; ww < 8; ++ww) s += ((facc4*)stg)[(ww * 64 + bl) * 4 + q];
        *(facc4*)&sumb_p[((size_t)at * B_DIM + bbase + bl) * 16 + q * 4] = s;
    }
}

// ---------------------------------------------------------------------------
// Kernel 3: node MLP for both sides, with inlined partial-sum reduction.
// a-side: 16 partials (bg tiles); b-side: 64 partials (at tiles).
// ---------------------------------------------------------------------------
__global__ __launch_bounds__(256) void node_kernel(
    const float* __restrict__ na, const float* __restrict__ nb,
    const float* __restrict__ suma_p, const float* __restrict__ sumb_p,
    const float* __restrict__ W1n, const float* __restrict__ b1n,
    const float* __restrict__ W2n, const float* __restrict__ b2n,
    float* __restrict__ out_a, float* __restrict__ out_b)
{
    __shared__ float W1_s[48 * 32];
    __shared__ float W2_s[32 * 32];
    __shared__ float hid_s[8][32];
    __shared__ float sx_s[8][16];
    int tid = threadIdx.x;
    for (int i = tid; i < 1536; i += 256) W1_s[i] = W1n[i];
    for (int i = tid; i < 1024; i += 256) W2_s[i] = W2n[i];
    int rlocal = tid >> 5;
    int r = blockIdx.x * 8 + rlocal;
    int j = tid & 31;
    int isb = (r >= 1024);
    int rr = isb ? r - 1024 : r;
    if (j < 16) {
        const float* P = isb ? sumb_p : suma_p;
        int np = isb ? 64 : 16;
        float acc = 0.f;
        for (int t = 0; t < np; ++t) acc += P[(size_t)t * 16384 + rr * 16 + j];
        sx_s[rlocal][j] = acc;
    }
    __syncthreads();
    const float* nx = (isb ? nb : na) + rr * 32;
    float acc = b1n[j];
    #pragma unroll
    for (int k = 0; k < 32; ++k) acc += nx[k] * W1_s[k * 32 + j];
    #pragma unroll
    for (int k = 0; k < 16; ++k) acc += sx_s[rlocal][k] * W1_s[(32 + k) * 32 + j];
    hid_s[rlocal][j] = fmaxf(acc, 0.f);
    __syncthreads();
    float acc2 = b2n[j];
    #pragma unroll
    for (int k = 0; k < 32; ++k) acc2 += hid_s[rlocal][k] * W2_s[k * 32 + j];
    (isb ? out_b : out_a)[rr * 32 + j] = fmaxf(acc2, 0.f);
}

extern "C" void kernel_launch(void* const* d_in, const int* in_sizes, int n_in,
                              void* d_out, int out_size, void* d_ws, size_t ws_size,
                              hipStream_t stream)
{
    const float* E   = (const float*)d_in[0];
    const float* na  = (const float*)d_in[1];
    const float* nb  = (const float*)d_in[2];
    const float* W1e = (const float*)d_in[3];
    const float* b1e = (const float*)d_in[4];
    const float* W2e = (const float*)d_in[5];
    const float* b2e = (const float*)d_in[6];
    const float* W1n = (const float*)d_in[7];
    const float* b1n = (const float*)d_in[8];
    const float* W2n = (const float*)d_in[9];
    const float* b2n = (const float*)d_in[10];

    float* out    = (float*)d_out;
    float* el_out = out;
    float* out_a  = out + (size_t)A_DIM * B_DIM * 16;
    float* out_b  = out_a + A_DIM * 32;

    float* ws     = (float*)d_ws;
    float* ha     = ws;                      // 16384
    float* hb     = ws + 16384;              // 16384
    float* suma_p = ws + 32768;              // 16 * 16384
    float* sumb_p = suma_p + 16 * 16384;     // 64 * 16384

    hipLaunchKernelGGL(prep_kernel, dim3(128), dim3(256), 0, stream,
                       na, nb, W1e, b1e, ha, hb);
    hipLaunchKernelGGL(edge_kernel, dim3(16, 64), dim3(512), 0, stream,
                       E, W1e, W2e, b2e, ha, hb, el_out, suma_p, sumb_p);
    hipLaunchKernelGGL(node_kernel, dim3(256), dim3(256), 0, stream,
                       na, nb, suma_p, sumb_p, W1n, b1n, W2n, b2n, out_a, out_b);
}

// Round 8
// 64.213 us; speedup vs baseline: 1.0014x; 1.0014x over previous
//
#include <hip/hip_runtime.h>

#define A_DIM 1024
#define B_DIM 1024

typedef __attribute__((ext_vector_type(8))) short bfrag8;
typedef __attribute__((ext_vector_type(4))) float facc4;
typedef const __attribute__((address_space(1))) unsigned GasPtr;
typedef __attribute__((address_space(3))) unsigned LdsPtr;

__device__ __forceinline__ unsigned short f2bf(float f) {
    unsigned u = __float_as_uint(f);
    u = (u + 0x7FFFu + ((u >> 16) & 1u)) >> 16;
    return (unsigned short)u;
}
__device__ __forceinline__ unsigned cvtpk(float lo, float hi) {
    unsigned r;
    asm("v_cvt_pk_bf16_f32 %0, %1, %2" : "=v"(r) : "v"(lo), "v"(hi));
    return r;
}

// ---------------------------------------------------------------------------
// Kernel 1: fused prep + edge MLP via MFMA.
// Grid (16 bg, 32 at) = 512 blocks x 8 waves x 70KB LDS -> 2 blocks/CU,
// 4096 waves = exact full residency (one round, no tail).
// Per wave: 4 a-rows = 8 half-tile steps; E staged via global_load_lds
// (wave-private 2x4KB double buffer), counted s_waitcnt vmcnt(N) =
// {4,6,8,8,8,8,8,4}, never 0 mid-loop, no barriers in the pipeline.
// Prep (ha/hb tiles) computed into LDS BEFORE the prologue stages; raw
// s_barrier (lgkmcnt(0) only) so the prologue DMAs stay in flight.
// LDS XOR-swizzle via pre-swizzled global source (slot s' = s ^ (row&7)):
// ds_read_b128 lands 2-way = free.
// C/D layout: col = lane&15 (edge), row = (lane>>4)*4 + reg (d).
// ---------------------------------------------------------------------------
__global__ __launch_bounds__(512, 4) void edge_kernel(
    const float* __restrict__ E, const float* __restrict__ na,
    const float* __restrict__ nb, const float* __restrict__ W1e,
    const float* __restrict__ b1e, const float* __restrict__ W2e,
    const float* __restrict__ b2e, float* __restrict__ el_out,
    float* __restrict__ suma_p, float* __restrict__ sumb_p)
{
    __shared__ __align__(16) float stg[8 * 2048];    // 64KB staging / combine
    __shared__ __align__(16) float ha_s[32 * 16];    // 2KB
    __shared__ __align__(16) float hb_s[64 * 16];    // 4KB

    const int tid  = threadIdx.x;
    const int lane = tid & 63;
    const int w    = tid >> 6;          // 0..7
    const int n    = lane & 15;
    const int g    = lane >> 4;
    const int bg   = blockIdx.x;        // 0..15
    const int at   = blockIdx.y;        // 0..31
    const int bbase = bg * 64;
    const int abase = at * 32;
    const int r0   = abase + w * 4;

    // staging geometry
    float* lbuf = stg + w * 2048;
    const int gswf = ((lane >> 3) * 32) + (((lane & 7) ^ ((lane >> 3) & 7)) * 4);
    const int xm   = n & 7;
    const int rdA0 = n * 32 + (((g * 2) ^ xm) * 4);
    const int rdA1 = n * 32 + ((((g * 2) | 1) ^ xm) * 4);
    const int rdB0 = rdA0 + 512;
    const int rdB1 = rdA1 + 512;

    // ---- weight fragments (loads drain with prep, before any DMA) ----
    bfrag8 w1f, w2f;
    #pragma unroll
    for (int t = 0; t < 8; ++t) {
        w1f[t] = (short)f2bf(W1e[(g * 8 + t) * 16 + n]);
        w2f[t] = (g < 2) ? (short)f2bf(W2e[(g * 8 + t) * 16 + n]) : (short)0;
    }
    facc4 b2f = *(const facc4*)&b2e[g * 4];

    // ---- inlined prep: ha (32x16), hb (64x16) into LDS ----
    {
        const int r = tid >> 4, d = tid & 15;
        const float* xa  = na + (abase + r) * 32;
        const float* xb0 = nb + (bbase + r) * 32;
        const float* xb1 = nb + (bbase + r + 32) * 32;
        float acca = b1e[d], accb0 = 0.f, accb1 = 0.f;
        #pragma unroll
        for (int k = 0; k < 32; ++k) {
            acca  += xa[k]  * W1e[(32 + k) * 16 + d];
            float wv = W1e[(64 + k) * 16 + d];
            accb0 += xb0[k] * wv;
            accb1 += xb1[k] * wv;
        }
        ha_s[r * 16 + d] = acca;
        hb_s[r * 16 + d] = accb0;
        hb_s[(r + 32) * 16 + d] = accb1;
    }
    asm volatile("s_waitcnt lgkmcnt(0)" ::: "memory");
    __builtin_amdgcn_sched_barrier(0);

#define STAGE(BUF, A, H)                                                       \
    {                                                                          \
        const float* tb_ = E + ((size_t)(A) * B_DIM + bbase + (H) * 32) * 32   \
                             + gswf;                                           \
        float* lb_ = lbuf + (BUF) * 1024;                                      \
        _Pragma("unroll")                                                      \
        for (int t_ = 0; t_ < 4; ++t_)                                         \
            __builtin_amdgcn_global_load_lds((GasPtr*)(tb_ + t_ * 256),        \
                                             (LdsPtr*)(lb_ + t_ * 256),        \
                                             16, 0, 0);                        \
        __builtin_amdgcn_sched_barrier(0);                                     \
    }

    // prologue: both halves of row r0 in flight ACROSS the raw barrier
    STAGE(0, r0, 0)
    STAGE(1, r0, 1)
    __builtin_amdgcn_s_barrier();

    // per-row / per-b fragments from LDS (lgkm only, DMAs untouched)
    facc4 hbF[4], haF[4];
    #pragma unroll
    for (int mt = 0; mt < 4; ++mt)
        hbF[mt] = *(const facc4*)&hb_s[(mt * 16 + n) * 16 + g * 4];
    #pragma unroll
    for (int i = 0; i < 4; ++i)
        haF[i] = *(const facc4*)&ha_s[(w * 4 + i) * 16 + g * 4];

    facc4 sumbA[4], sumaR[4];
    #pragma unroll
    for (int mt = 0; mt < 4; ++mt) {
        sumbA[mt] = facc4{0.f, 0.f, 0.f, 0.f};
        sumaR[mt] = facc4{0.f, 0.f, 0.f, 0.f};
    }
    facc4 ssum = facc4{0.f, 0.f, 0.f, 0.f};

#define PVTILE(V0, V1, MT, A, RI)                                              \
    {                                                                          \
        union { unsigned u[4]; bfrag8 s; } ef_;                                \
        ef_.u[0] = cvtpk(V0.x, V0.y); ef_.u[1] = cvtpk(V0.z, V0.w);            \
        ef_.u[2] = cvtpk(V1.x, V1.y); ef_.u[3] = cvtpk(V1.z, V1.w);            \
        facc4 h_ = __builtin_amdgcn_mfma_f32_16x16x32_bf16(                    \
            w1f, ef_.s, haF[RI] + hbF[MT], 0, 0, 0);                           \
        h_.x = fmaxf(h_.x, 0.f); h_.y = fmaxf(h_.y, 0.f);                      \
        h_.z = fmaxf(h_.z, 0.f); h_.w = fmaxf(h_.w, 0.f);                      \
        const int sl_ = (n + g * 32) & 63;                                     \
        const int sh_ = (n + g * 32 + 16) & 63;                                \
        float v0_ = __shfl(h_.x, sl_), v1_ = __shfl(h_.y, sl_);                \
        float v2_ = __shfl(h_.z, sl_), v3_ = __shfl(h_.w, sl_);                \
        float u0_ = __shfl(h_.x, sh_), u1_ = __shfl(h_.y, sh_);                \
        float u2_ = __shfl(h_.z, sh_), u3_ = __shfl(h_.w, sh_);                \
        union { unsigned u[4]; bfrag8 s; } bb_;                                \
        bb_.u[0] = cvtpk(v0_, v1_); bb_.u[1] = cvtpk(v2_, v3_);                \
        bb_.u[2] = cvtpk(u0_, u1_); bb_.u[3] = cvtpk(u2_, u3_);                \
        facc4 e_ = __builtin_amdgcn_mfma_f32_16x16x32_bf16(                    \
            w2f, bb_.s, b2f, 0, 0, 0);                                         \
        e_.x = fmaxf(e_.x, 0.f); e_.y = fmaxf(e_.y, 0.f);                      \
        e_.z = fmaxf(e_.z, 0.f); e_.w = fmaxf(e_.w, 0.f);                      \
        facc4* op_ = (facc4*)&el_out[((size_t)(A) * B_DIM + bbase              \
                                      + (MT) * 16 + n) * 16 + g * 4];          \
        __builtin_nontemporal_store(e_, op_);                                  \
        sumbA[MT] += e_;                                                       \
        ssum += e_;                                                            \
    }

#define STEP(BUF, AROW, RI, H, VM, DOSTAGE, NA, NH)                            \
    {                                                                          \
        asm volatile("s_waitcnt vmcnt(" #VM ")" ::: "memory");                 \
        __builtin_amdgcn_sched_barrier(0);                                     \
        float* lb_ = lbuf + (BUF) * 1024;                                      \
        facc4 vA0 = *(facc4*)(lb_ + rdA0);                                     \
        facc4 vA1 = *(facc4*)(lb_ + rdA1);                                     \
        facc4 vB0 = *(facc4*)(lb_ + rdB0);                                     \
        facc4 vB1 = *(facc4*)(lb_ + rdB1);                                     \
        asm volatile("s_waitcnt lgkmcnt(0)" ::: "memory");                     \
        __builtin_amdgcn_sched_barrier(0);                                     \
        if (DOSTAGE) { STAGE(BUF, NA, NH) }                                    \
        if ((H) == 0) ssum = facc4{0.f, 0.f, 0.f, 0.f};                        \
        PVTILE(vA0, vA1, (2 * (H)),     AROW, RI)                              \
        PVTILE(vB0, vB1, (2 * (H) + 1), AROW, RI)                              \
        if ((H) == 1) {                                                        \
            _Pragma("unroll")                                                  \
            for (int m_ = 1; m_ <= 8; m_ <<= 1) {                              \
                ssum.x += __shfl_xor(ssum.x, m_);                              \
                ssum.y += __shfl_xor(ssum.y, m_);                              \
                ssum.z += __shfl_xor(ssum.z, m_);                              \
                ssum.w += __shfl_xor(ssum.w, m_);                              \
            }                                                                  \
            sumaR[RI] = ssum;                                                  \
        }                                                                      \
    }

    // 8-step pipeline; stage H_{s+2} into the buffer just consumed
    STEP(0, r0,     0, 0, 4, 1, r0 + 1, 0)
    STEP(1, r0,     0, 1, 6, 1, r0 + 1, 1)
    STEP(0, r0 + 1, 1, 0, 8, 1, r0 + 2, 0)
    STEP(1, r0 + 1, 1, 1, 8, 1, r0 + 2, 1)
    STEP(0, r0 + 2, 2, 0, 8, 1, r0 + 3, 0)
    STEP(1, r0 + 2, 2, 1, 8, 1, r0 + 3, 1)
    STEP(0, r0 + 3, 3, 0, 8, 0, 0, 0)
    STEP(1, r0 + 3, 3, 1, 4, 0, 0, 0)

#undef STAGE
#undef PVTILE
#undef STEP

    if (n == 0) {
        *(facc4*)&suma_p[((size_t)bg * A_DIM + r0)     * 16 + g * 4] = sumaR[0];
        *(facc4*)&suma_p[((size_t)bg * A_DIM + r0 + 1) * 16 + g * 4] = sumaR[1];
        *(facc4*)&suma_p[((size_t)bg * A_DIM + r0 + 2) * 16 + g * 4] = sumaR[2];
        *(facc4*)&suma_p[((size_t)bg * A_DIM + r0 + 3) * 16 + g * 4] = sumaR[3];
    }

    // ---- combine sumb across 8 waves (reuse staging LDS, 32KB) ----
    __syncthreads();
    #pragma unroll
    for (int mt = 0; mt < 4; ++mt)
        ((facc4*)stg)[(w * 64 + mt * 16 + n) * 4 + g] = sumbA[mt];
    __syncthreads();
    if (tid < 256) {
        const int bl = tid >> 2, q = tid & 3;
        facc4 s = facc4{0.f, 0.f, 0.f, 0.f};
        #pragma unroll
        for (int ww = 0; ww < 8; ++ww) s += ((facc4*)stg)[(ww * 64 + bl) * 4 + q];
        *(facc4*)&sumb_p[((size_t)at * B_DIM + bbase + bl) * 16 + q * 4] = s;
    }
}

// ---------------------------------------------------------------------------
// Kernel 2: node MLP for both sides, with inlined partial-sum reduction.
// a-side: 16 partials (bg tiles); b-side: 32 partials (at tiles).
// ---------------------------------------------------------------------------
__global__ __launch_bounds__(256) void node_kernel(
    const float* __restrict__ na, const float* __restrict__ nb,
    const float* __restrict__ suma_p, const float* __restrict__ sumb_p,
    const float* __restrict__ W1n, const float* __restrict__ b1n,
    const float* __restrict__ W2n, const float* __restrict__ b2n,
    float* __restrict__ out_a, float* __restrict__ out_b)
{
    __shared__ float W1_s[48 * 32];
    __shared__ float W2_s[32 * 32];
    __shared__ float hid_s[8][32];
    __shared__ float sx_s[8][16];
    int tid = threadIdx.x;
    for (int i = tid; i < 1536; i += 256) W1_s[i] = W1n[i];
    for (int i = tid; i < 1024; i += 256) W2_s[i] = W2n[i];
    int rlocal = tid >> 5;
    int r = blockIdx.x * 8 + rlocal;
    int j = tid & 31;
    int isb = (r >= 1024);
    int rr = isb ? r - 1024 : r;
    if (j < 16) {
        const float* P = isb ? sumb_p : suma_p;
        int np = isb ? 32 : 16;
        float acc = 0.f;
        for (int t = 0; t < np; ++t) acc += P[(size_t)t * 16384 + rr * 16 + j];
        sx_s[rlocal][j] = acc;
    }
    __syncthreads();
    const float* nx = (isb ? nb : na) + rr * 32;
    float acc = b1n[j];
    #pragma unroll
    for (int k = 0; k < 32; ++k) acc += nx[k] * W1_s[k * 32 + j];
    #pragma unroll
    for (int k = 0; k < 16; ++k) acc += sx_s[rlocal][k] * W1_s[(32 + k) * 32 + j];
    hid_s[rlocal][j] = fmaxf(acc, 0.f);
    __syncthreads();
    float acc2 = b2n[j];
    #pragma unroll
    for (int k = 0; k < 32; ++k) acc2 += hid_s[rlocal][k] * W2_s[k * 32 + j];
    (isb ? out_b : out_a)[rr * 32 + j] = fmaxf(acc2, 0.f);
}

extern "C" void kernel_launch(void* const* d_in, const int* in_sizes, int n_in,
                              void* d_out, int out_size, void* d_ws, size_t ws_size,
                              hipStream_t stream)
{
    const float* E   = (const float*)d_in[0];
    const float* na  = (const float*)d_in[1];
    const float* nb  = (const float*)d_in[2];
    const float* W1e = (const float*)d_in[3];
    const float* b1e = (const float*)d_in[4];
    const float* W2e = (const float*)d_in[5];
    const float* b2e = (const float*)d_in[6];
    const float* W1n = (const float*)d_in[7];
    const float* b1n = (const float*)d_in[8];
    const float* W2n = (const float*)d_in[9];
    const float* b2n = (const float*)d_in[10];

    float* out    = (float*)d_out;
    float* el_out = out;
    float* out_a  = out + (size_t)A_DIM * B_DIM * 16;
    float* out_b  = out_a + A_DIM * 32;

    float* ws     = (float*)d_ws;
    float* suma_p = ws;                      // 16 * 16384
    float* sumb_p = ws + 16 * 16384;         // 32 * 16384

    hipLaunchKernelGGL(edge_kernel, dim3(16, 32), dim3(512), 0, stream,
                       E, na, nb, W1e, b1e, W2e, b2e, el_out, suma_p, sumb_p);
    hipLaunchKernelGGL(node_kernel, dim3(256), dim3(256), 0, stream,
                       na, nb, suma_p, sumb_p, W1n, b1n, W2n, b2n, out_a, out_b);
}

// Round 9
// 59.649 us; speedup vs baseline: 1.0781x; 1.0765x over previous
//
#include <hip/hip_runtime.h>

#define A_DIM 1024
#define B_DIM 1024

typedef __attribute__((ext_vector_type(8))) short bfrag8;
typedef __attribute__((ext_vector_type(4))) float facc4;

__device__ __forceinline__ unsigned short f2bf(float f) {
    unsigned u = __float_as_uint(f);
    u = (u + 0x7FFFu + ((u >> 16) & 1u)) >> 16;
    return (unsigned short)u;
}
__device__ __forceinline__ unsigned cvtpk(float lo, float hi) {
    unsigned r;
    asm("v_cvt_pk_bf16_f32 %0, %1, %2" : "=v"(r) : "v"(lo), "v"(hi));
    return r;
}

// ---------------------------------------------------------------------------
// Kernel 1: fused prep + edge MLP via MFMA, mt-split waves for low VGPR.
// Grid (16 bg, 64 at) = 1024 blocks x 512 thr (8 waves). Block: 64 b x 16 a.
// Wave w: b-half mh = w&1 (mt tiles 2mh, 2mh+1 = 32 b's), rows r0 = at*16 +
// (w>>1)*4 .. +3. 4 steps, half-row buffers (16 VGPR each) in a TRUE 2-deep
// ping-pong: loads for step s+1 issued before compute of step s, so every
// wave keeps >=4KB in flight continuously. Total per-wave state ~60 VGPR ->
// survives the allocator's 64-reg squeeze without serializing (the R3/R6/R8
// failure). Prep: inputs staged coalesced into (reused) sb LDS, dots read
// LDS broadcasts only. C/D layout: col = lane&15 (edge), row=(lane>>4)*4+reg.
// ---------------------------------------------------------------------------
__global__ __launch_bounds__(512, 5) void edge_kernel(
    const float* __restrict__ E, const float* __restrict__ na,
    const float* __restrict__ nb, const float* __restrict__ W1e,
    const float* __restrict__ b1e, const float* __restrict__ W2e,
    const float* __restrict__ b2e, float* __restrict__ el_out,
    float* __restrict__ suma_p, float* __restrict__ sumb_p)
{
    __shared__ __align__(16) float sb[8 * 32 * 16];   // 16 KB: prep stage / combine
    __shared__ __align__(16) float ha_s[16 * 16];
    __shared__ __align__(16) float hb_s[64 * 16];

    const int tid  = threadIdx.x;
    const int lane = tid & 63;
    const int w    = tid >> 6;          // 0..7
    const int n    = lane & 15;
    const int g    = lane >> 4;
    const int bg   = blockIdx.x;        // 0..15
    const int at   = blockIdx.y;        // 0..63
    const int bbase = bg * 64;
    const int abase = at * 16;
    const int mh   = w & 1;             // b-half: mt tiles {2mh, 2mh+1}
    const int rg   = w >> 1;            // 0..3
    const int r0   = abase + rg * 4;
    const int mt0  = mh * 2, mt1 = mh * 2 + 1;

    float4 bufA[4], bufB[4];

#define LOADH(BUF, AROW)                                                       \
    {                                                                          \
        const float* p_  = E + ((size_t)(AROW) * B_DIM + bbase) * 32;          \
        const float* p0_ = p_ + (mt0 * 16 + n) * 32 + g * 8;                   \
        const float* p1_ = p_ + (mt1 * 16 + n) * 32 + g * 8;                   \
        BUF[0] = *(const float4*)p0_;  BUF[1] = *(const float4*)(p0_ + 4);     \
        BUF[2] = *(const float4*)p1_;  BUF[3] = *(const float4*)(p1_ + 4);     \
    }

    // step-0 loads first: HBM latency hides under prep
    LOADH(bufA, r0)

    // ---- prep stage: na tile / nb tile / W1e[32..96) into LDS, coalesced ----
    float* xa_s = sb;                 // 16*32 f32
    float* xb_s = sb + 512;           // 64*32 f32
    float* wq_s = sb + 512 + 2048;    // 64*16 f32  (W1e rows 32..95)
    if (tid < 128)
        ((float4*)xa_s)[tid] = ((const float4*)(na + (size_t)abase * 32))[tid];
    ((float4*)xb_s)[tid] = ((const float4*)(nb + (size_t)bbase * 32))[tid];
    if (tid < 256)
        ((float4*)wq_s)[tid] = ((const float4*)(W1e + 32 * 16))[tid];

    // weight fragments (global, L1-hot; independent of LDS stage)
    bfrag8 w1f, w2f;
    #pragma unroll
    for (int t = 0; t < 8; ++t) {
        w1f[t] = (short)f2bf(W1e[(g * 8 + t) * 16 + n]);
        w2f[t] = (g < 2) ? (short)f2bf(W2e[(g * 8 + t) * 16 + n]) : (short)0;
    }
    facc4 b2f = *(const facc4*)&b2e[g * 4];
    __syncthreads();

    // ---- prep compute: all operands LDS-broadcast ----
    {
        const int r = tid >> 4, d = tid & 15;   // r 0..31
        if (r < 16) {
            float acca = b1e[d];
            #pragma unroll
            for (int k = 0; k < 32; ++k)
                acca += xa_s[r * 32 + k] * wq_s[k * 16 + d];
            ha_s[r * 16 + d] = acca;
        }
        float ab0 = 0.f, ab1 = 0.f;
        #pragma unroll
        for (int k = 0; k < 32; ++k) {
            float wv = wq_s[(32 + k) * 16 + d];
            ab0 += xb_s[r * 32 + k] * wv;
            ab1 += xb_s[(r + 32) * 32 + k] * wv;
        }
        hb_s[r * 16 + d] = ab0;
        hb_s[(r + 32) * 16 + d] = ab1;
    }
    __syncthreads();

    facc4 hbF0 = *(const facc4*)&hb_s[(mt0 * 16 + n) * 16 + g * 4];
    facc4 hbF1 = *(const facc4*)&hb_s[(mt1 * 16 + n) * 16 + g * 4];
    facc4 sumb0 = facc4{0.f, 0.f, 0.f, 0.f};
    facc4 sumb1 = facc4{0.f, 0.f, 0.f, 0.f};

#define PVTILE(V0, V1, MT, HBF, SUMB, AROW, HAF)                               \
    {                                                                          \
        union { unsigned u[4]; bfrag8 s; } ef_;                                \
        ef_.u[0] = cvtpk((V0).x, (V0).y); ef_.u[1] = cvtpk((V0).z, (V0).w);    \
        ef_.u[2] = cvtpk((V1).x, (V1).y); ef_.u[3] = cvtpk((V1).z, (V1).w);    \
        facc4 h_ = __builtin_amdgcn_mfma_f32_16x16x32_bf16(                    \
            w1f, ef_.s, (HAF) + (HBF), 0, 0, 0);                               \
        h_.x = fmaxf(h_.x, 0.f); h_.y = fmaxf(h_.y, 0.f);                      \
        h_.z = fmaxf(h_.z, 0.f); h_.w = fmaxf(h_.w, 0.f);                      \
        const int sl_ = (n + g * 32) & 63;                                     \
        const int sh_ = (n + g * 32 + 16) & 63;                                \
        float v0_ = __shfl(h_.x, sl_), v1_ = __shfl(h_.y, sl_);                \
        float v2_ = __shfl(h_.z, sl_), v3_ = __shfl(h_.w, sl_);                \
        float u0_ = __shfl(h_.x, sh_), u1_ = __shfl(h_.y, sh_);                \
        float u2_ = __shfl(h_.z, sh_), u3_ = __shfl(h_.w, sh_);                \
        union { unsigned u[4]; bfrag8 s; } bb_;                                \
        bb_.u[0] = cvtpk(v0_, v1_); bb_.u[1] = cvtpk(v2_, v3_);                \
        bb_.u[2] = cvtpk(u0_, u1_); bb_.u[3] = cvtpk(u2_, u3_);                \
        facc4 e_ = __builtin_amdgcn_mfma_f32_16x16x32_bf16(                    \
            w2f, bb_.s, b2f, 0, 0, 0);                                         \
        e_.x = fmaxf(e_.x, 0.f); e_.y = fmaxf(e_.y, 0.f);                      \
        e_.z = fmaxf(e_.z, 0.f); e_.w = fmaxf(e_.w, 0.f);                      \
        *(facc4*)&el_out[((size_t)(AROW) * B_DIM + bbase + (MT) * 16 + n)      \
                         * 16 + g * 4] = e_;                                   \
        SUMB += e_;                                                            \
        ssum += e_;                                                            \
    }

#define COMPUTE(BUF, AROW, S)                                                  \
    {                                                                          \
        facc4 haf_ = *(const facc4*)&ha_s[(rg * 4 + (S)) * 16 + g * 4];        \
        facc4 ssum = facc4{0.f, 0.f, 0.f, 0.f};                                \
        PVTILE(BUF[0], BUF[1], mt0, hbF0, sumb0, AROW, haf_)                   \
        PVTILE(BUF[2], BUF[3], mt1, hbF1, sumb1, AROW, haf_)                   \
        _Pragma("unroll")                                                      \
        for (int m_ = 1; m_ <= 8; m_ <<= 1) {                                  \
            ssum.x += __shfl_xor(ssum.x, m_);                                  \
            ssum.y += __shfl_xor(ssum.y, m_);                                  \
            ssum.z += __shfl_xor(ssum.z, m_);                                  \
            ssum.w += __shfl_xor(ssum.w, m_);                                  \
        }                                                                      \
        if (n == 0)                                                            \
            *(facc4*)&suma_p[((size_t)(bg * 2 + mh) * A_DIM + (AROW)) * 16     \
                             + g * 4] = ssum;                                  \
    }

    // 2-deep ping-pong: step s+1 loads in flight during step s compute
    LOADH(bufB, r0 + 1)
    COMPUTE(bufA, r0, 0)
    LOADH(bufA, r0 + 2)
    COMPUTE(bufB, r0 + 1, 1)
    LOADH(bufB, r0 + 3)
    COMPUTE(bufA, r0 + 2, 2)
    COMPUTE(bufB, r0 + 3, 3)

#undef LOADH
#undef PVTILE
#undef COMPUTE

    // ---- sumb combine across the 4 waves sharing each b-half ----
    __syncthreads();
    *(facc4*)&sb[((w * 32 + n) * 4 + g) * 4]      = sumb0;
    *(facc4*)&sb[((w * 32 + 16 + n) * 4 + g) * 4] = sumb1;
    __syncthreads();
    if (tid < 256) {
        const int b = tid >> 2, q = tid & 3;
        const int mh2 = b >> 5, rest = b & 31;
        facc4 s = facc4{0.f, 0.f, 0.f, 0.f};
        #pragma unroll
        for (int rg2 = 0; rg2 < 4; ++rg2)
            s += *(const facc4*)&sb[(((rg2 * 2 + mh2) * 32 + rest) * 4 + q) * 4];
        *(facc4*)&sumb_p[((size_t)at * B_DIM + bbase + b) * 16 + q * 4] = s;
    }
}

// ---------------------------------------------------------------------------
// Kernel 2: node MLP for both sides, inlined 2-way-split partial reduction.
// a-side: 32 partials (bg x mh); b-side: 64 partials (at).
// ---------------------------------------------------------------------------
__global__ __launch_bounds__(256) void node_kernel(
    const float* __restrict__ na, const float* __restrict__ nb,
    const float* __restrict__ suma_p, const float* __restrict__ sumb_p,
    const float* __restrict__ W1n, const float* __restrict__ b1n,
    const float* __restrict__ W2n, const float* __restrict__ b2n,
    float* __restrict__ out_a, float* __restrict__ out_b)
{
    __shared__ float W1_s[48 * 32];
    __shared__ float W2_s[32 * 32];
    __shared__ float hid_s[8][32];
    __shared__ float sx2[8][32];
    __shared__ float sx_s[8][16];
    int tid = threadIdx.x;
    for (int i = tid; i < 1536; i += 256) W1_s[i] = W1n[i];
    for (int i = tid; i < 1024; i += 256) W2_s[i] = W2n[i];
    int rlocal = tid >> 5;
    int r = blockIdx.x * 8 + rlocal;
    int j = tid & 31;
    int isb = (r >= 1024);
    int rr = isb ? r - 1024 : r;
    {
        const float* P = isb ? sumb_p : suma_p;
        int hn = isb ? 32 : 16;           // half of partial count
        int d = j & 15, hf = j >> 4;
        float acc = 0.f;
        for (int t = hf * hn; t < hf * hn + hn; ++t)
            acc += P[(size_t)t * 16384 + rr * 16 + d];
        sx2[rlocal][j] = acc;
    }
    __syncthreads();
    if (j < 16) sx_s[rlocal][j] = sx2[rlocal][j] + sx2[rlocal][j + 16];
    __syncthreads();
    const float* nx = (isb ? nb : na) + rr * 32;
    float acc = b1n[j];
    #pragma unroll
    for (int k = 0; k < 32; ++k) acc += nx[k] * W1_s[k * 32 + j];
    #pragma unroll
    for (int k = 0; k < 16; ++k) acc += sx_s[rlocal][k] * W1_s[(32 + k) * 32 + j];
    hid_s[rlocal][j] = fmaxf(acc, 0.f);
    __syncthreads();
    float acc2 = b2n[j];
    #pragma unroll
    for (int k = 0; k < 32; ++k) acc2 += hid_s[rlocal][k] * W2_s[k * 32 + j];
    (isb ? out_b : out_a)[rr * 32 + j] = fmaxf(acc2, 0.f);
}

extern "C" void kernel_launch(void* const* d_in, const int* in_sizes, int n_in,
                              void* d_out, int out_size, void* d_ws, size_t ws_size,
                              hipStream_t stream)
{
    const float* E   = (const float*)d_in[0];
    const float* na  = (const float*)d_in[1];
    const float* nb  = (const float*)d_in[2];
    const float* W1e = (const float*)d_in[3];
    const float* b1e = (const float*)d_in[4];
    const float* W2e = (const float*)d_in[5];
    const float* b2e = (const float*)d_in[6];
    const float* W1n = (const float*)d_in[7];
    const float* b1n = (const float*)d_in[8];
    const float* W2n = (const float*)d_in[9];
    const float* b2n = (const float*)d_in[10];

    float* out    = (float*)d_out;
    float* el_out = out;
    float* out_a  = out + (size_t)A_DIM * B_DIM * 16;
    float* out_b  = out_a + A_DIM * 32;

    float* ws     = (float*)d_ws;
    float* suma_p = ws;                      // 32 * 16384
    float* sumb_p = ws + 32 * 16384;         // 64 * 16384

    hipLaunchKernelGGL(edge_kernel, dim3(16, 64), dim3(512), 0, stream,
                       E, na, nb, W1e, b1e, W2e, b2e, el_out, suma_p, sumb_p);
    hipLaunchKernelGGL(node_kernel, dim3(256), dim3(256), 0, stream,
                       na, nb, suma_p, sumb_p, W1n, b1n, W2n, b2n, out_a, out_b);
}

// Round 10
// 55.723 us; speedup vs baseline: 1.1540x; 1.0705x over previous
//
#include <hip/hip_runtime.h>

#define A_DIM 1024
#define B_DIM 1024

typedef __attribute__((ext_vector_type(8))) short bfrag8;
typedef __attribute__((ext_vector_type(4))) float facc4;

__device__ __forceinline__ unsigned short f2bf(float f) {
    unsigned u = __float_as_uint(f);
    u = (u + 0x7FFFu + ((u >> 16) & 1u)) >> 16;
    return (unsigned short)u;
}
__device__ __forceinline__ unsigned cvtpk(float lo, float hi) {
    unsigned r;
    asm("v_cvt_pk_bf16_f32 %0, %1, %2" : "=v"(r) : "v"(lo), "v"(hi));
    return r;
}

// ---------------------------------------------------------------------------
// Kernel 1: fused prep + edge MLP via MFMA, mt-split waves, REGISTER-PINNED
// 2-deep pipeline: loads are inline-asm global_load_dwordx4 (allocator must
// keep both buffers live; volatile asm cannot be rematerialized - the R3/R6/
// R8/R9 failure), stores are asm global_store_dwordx4 so counted
// s_waitcnt vmcnt(N) = {4,7,7,3} is exact (in-order vmcnt retirement).
// sched_barrier(0) after every wait stops MFMA hoisting past it (rule #18).
// Grid (16 bg, 64 at) x 512 thr (8 waves). Wave w: b-half mh=w&1 (mt 2mh,
// 2mh+1), rows r0..r0+3. Prep (ha/hb) via LDS-staged inputs, fused.
// C/D layout: col = lane&15 (edge), row = (lane>>4)*4 + reg.
// ---------------------------------------------------------------------------
__global__ __launch_bounds__(512, 4) void edge_kernel(
    const float* __restrict__ E, const float* __restrict__ na,
    const float* __restrict__ nb, const float* __restrict__ W1e,
    const float* __restrict__ b1e, const float* __restrict__ W2e,
    const float* __restrict__ b2e, float* __restrict__ el_out,
    float* __restrict__ suma_p, float* __restrict__ sumb_p)
{
    __shared__ __align__(16) float sb[8 * 32 * 16];   // 16 KB: prep stage / combine
    __shared__ __align__(16) float ha_s[16 * 16];
    __shared__ __align__(16) float hb_s[64 * 16];

    const int tid  = threadIdx.x;
    const int lane = tid & 63;
    const int w    = tid >> 6;          // 0..7
    const int n    = lane & 15;
    const int g    = lane >> 4;
    const int bg   = blockIdx.x;        // 0..15
    const int at   = blockIdx.y;        // 0..63
    const int bbase = bg * 64;
    const int abase = at * 16;
    const int mh   = w & 1;
    const int rg   = w >> 1;
    const int r0   = abase + rg * 4;
    const int mt0  = mh * 2, mt1 = mh * 2 + 1;

    float4 bufA[4], bufB[4];

#define LOADH(BUF, AROW)                                                       \
    {                                                                          \
        const float* p_  = E + ((size_t)(AROW) * B_DIM + bbase) * 32;          \
        const float* p0_ = p_ + (mt0 * 16 + n) * 32 + g * 8;                   \
        const float* p1_ = p_ + (mt1 * 16 + n) * 32 + g * 8;                   \
        asm volatile("global_load_dwordx4 %0, %1, off"                         \
                     : "=v"(BUF[0]) : "v"(p0_) : "memory");                    \
        asm volatile("global_load_dwordx4 %0, %1, off"                         \
                     : "=v"(BUF[1]) : "v"(p0_ + 4) : "memory");                \
        asm volatile("global_load_dwordx4 %0, %1, off"                         \
                     : "=v"(BUF[2]) : "v"(p1_) : "memory");                    \
        asm volatile("global_load_dwordx4 %0, %1, off"                         \
                     : "=v"(BUF[3]) : "v"(p1_ + 4) : "memory");                \
    }

    // ---- prep stage: na tile / nb tile / W1e[32..96) into LDS, coalesced ----
    float* xa_s = sb;                 // 16*32 f32
    float* xb_s = sb + 512;           // 64*32 f32
    float* wq_s = sb + 512 + 2048;    // 64*16 f32  (W1e rows 32..95)
    if (tid < 128)
        ((float4*)xa_s)[tid] = ((const float4*)(na + (size_t)abase * 32))[tid];
    ((float4*)xb_s)[tid] = ((const float4*)(nb + (size_t)bbase * 32))[tid];
    if (tid < 256)
        ((float4*)wq_s)[tid] = ((const float4*)(W1e + 32 * 16))[tid];

    // weight fragments (global, L1-hot; complete before the pipeline drain)
    bfrag8 w1f, w2f;
    #pragma unroll
    for (int t = 0; t < 8; ++t) {
        w1f[t] = (short)f2bf(W1e[(g * 8 + t) * 16 + n]);
        w2f[t] = (g < 2) ? (short)f2bf(W2e[(g * 8 + t) * 16 + n]) : (short)0;
    }
    facc4 b2f = *(const facc4*)&b2e[g * 4];
    __syncthreads();

    // ---- prep compute: all operands LDS-broadcast ----
    {
        const int r = tid >> 4, d = tid & 15;   // r 0..31
        if (r < 16) {
            float acca = b1e[d];
            #pragma unroll
            for (int k = 0; k < 32; ++k)
                acca += xa_s[r * 32 + k] * wq_s[k * 16 + d];
            ha_s[r * 16 + d] = acca;
        }
        float ab0 = 0.f, ab1 = 0.f;
        #pragma unroll
        for (int k = 0; k < 32; ++k) {
            float wv = wq_s[(32 + k) * 16 + d];
            ab0 += xb_s[r * 32 + k] * wv;
            ab1 += xb_s[(r + 32) * 32 + k] * wv;
        }
        hb_s[r * 16 + d] = ab0;
        hb_s[(r + 32) * 16 + d] = ab1;
    }
    __syncthreads();

    facc4 hbF0 = *(const facc4*)&hb_s[(mt0 * 16 + n) * 16 + g * 4];
    facc4 hbF1 = *(const facc4*)&hb_s[(mt1 * 16 + n) * 16 + g * 4];
    facc4 haF[4];
    #pragma unroll
    for (int i = 0; i < 4; ++i)
        haF[i] = *(const facc4*)&ha_s[(rg * 4 + i) * 16 + g * 4];
    facc4 sumb0 = facc4{0.f, 0.f, 0.f, 0.f};
    facc4 sumb1 = facc4{0.f, 0.f, 0.f, 0.f};

#define PVTILE(V0, V1, MT, HBF, SUMB, AROW, HAF)                               \
    {                                                                          \
        union { unsigned u[4]; bfrag8 s; } ef_;                                \
        ef_.u[0] = cvtpk((V0).x, (V0).y); ef_.u[1] = cvtpk((V0).z, (V0).w);    \
        ef_.u[2] = cvtpk((V1).x, (V1).y); ef_.u[3] = cvtpk((V1).z, (V1).w);    \
        facc4 h_ = __builtin_amdgcn_mfma_f32_16x16x32_bf16(                    \
            w1f, ef_.s, (HAF) + (HBF), 0, 0, 0);                               \
        h_.x = fmaxf(h_.x, 0.f); h_.y = fmaxf(h_.y, 0.f);                      \
        h_.z = fmaxf(h_.z, 0.f); h_.w = fmaxf(h_.w, 0.f);                      \
        const int sl_ = (n + g * 32) & 63;                                     \
        const int sh_ = (n + g * 32 + 16) & 63;                                \
        float v0_ = __shfl(h_.x, sl_), v1_ = __shfl(h_.y, sl_);                \
        float v2_ = __shfl(h_.z, sl_), v3_ = __shfl(h_.w, sl_);                \
        float u0_ = __shfl(h_.x, sh_), u1_ = __shfl(h_.y, sh_);                \
        float u2_ = __shfl(h_.z, sh_), u3_ = __shfl(h_.w, sh_);                \
        union { unsigned u[4]; bfrag8 s; } bb_;                                \
        bb_.u[0] = cvtpk(v0_, v1_); bb_.u[1] = cvtpk(v2_, v3_);                \
        bb_.u[2] = cvtpk(u0_, u1_); bb_.u[3] = cvtpk(u2_, u3_);                \
        facc4 e_ = __builtin_amdgcn_mfma_f32_16x16x32_bf16(                    \
            w2f, bb_.s, b2f, 0, 0, 0);                                         \
        e_.x = fmaxf(e_.x, 0.f); e_.y = fmaxf(e_.y, 0.f);                      \
        e_.z = fmaxf(e_.z, 0.f); e_.w = fmaxf(e_.w, 0.f);                      \
        float* op_ = &el_out[((size_t)(AROW) * B_DIM + bbase + (MT) * 16 + n)  \
                             * 16 + g * 4];                                    \
        asm volatile("global_store_dwordx4 %0, %1, off"                        \
                     :: "v"(op_), "v"(e_) : "memory");                         \
        SUMB += e_;                                                            \
        ssum += e_;                                                            \
    }

#define COMPUTE(BUF, AROW, S)                                                  \
    {                                                                          \
        facc4 ssum = facc4{0.f, 0.f, 0.f, 0.f};                                \
        PVTILE(BUF[0], BUF[1], mt0, hbF0, sumb0, AROW, haF[S])                 \
        PVTILE(BUF[2], BUF[3], mt1, hbF1, sumb1, AROW, haF[S])                 \
        _Pragma("unroll")                                                      \
        for (int m_ = 1; m_ <= 8; m_ <<= 1) {                                  \
            ssum.x += __shfl_xor(ssum.x, m_);                                  \
            ssum.y += __shfl_xor(ssum.y, m_);                                  \
            ssum.z += __shfl_xor(ssum.z, m_);                                  \
            ssum.w += __shfl_xor(ssum.w, m_);                                  \
        }                                                                      \
        if (n == 0) {                                                          \
            float* sp_ = &suma_p[((size_t)(bg * 2 + mh) * A_DIM + (AROW)) * 16 \
                                 + g * 4];                                     \
            asm volatile("global_store_dwordx4 %0, %1, off"                    \
                         :: "v"(sp_), "v"(ssum) : "memory");                   \
        }                                                                      \
    }

#define WAITV(N)                                                               \
    asm volatile("s_waitcnt vmcnt(" #N ")" ::: "memory");                      \
    __builtin_amdgcn_sched_barrier(0);

    // clean slate: no prep vmem outstanding -> counts below are exact
    WAITV(0)

    // pinned 2-deep pipeline.  queue math (4 loads/stage, 3 stores/step):
    //   LA4 LB4 |w4| C0(st3) LA4 |w7| C1(st3) LB4 |w7| C2(st3) |w3| C3
    LOADH(bufA, r0)
    LOADH(bufB, r0 + 1)
    WAITV(4)
    COMPUTE(bufA, r0, 0)
    LOADH(bufA, r0 + 2)
    WAITV(7)
    COMPUTE(bufB, r0 + 1, 1)
    LOADH(bufB, r0 + 3)
    WAITV(7)
    COMPUTE(bufA, r0 + 2, 2)
    WAITV(3)
    COMPUTE(bufB, r0 + 3, 3)

#undef LOADH
#undef PVTILE
#undef COMPUTE
#undef WAITV

    // ---- sumb combine across the 4 waves sharing each b-half ----
    __syncthreads();
    *(facc4*)&sb[((w * 32 + n) * 4 + g) * 4]      = sumb0;
    *(facc4*)&sb[((w * 32 + 16 + n) * 4 + g) * 4] = sumb1;
    __syncthreads();
    if (tid < 256) {
        const int b = tid >> 2, q = tid & 3;
        const int mh2 = b >> 5, rest = b & 31;
        facc4 s = facc4{0.f, 0.f, 0.f, 0.f};
        #pragma unroll
        for (int rg2 = 0; rg2 < 4; ++rg2)
            s += *(const facc4*)&sb[(((rg2 * 2 + mh2) * 32 + rest) * 4 + q) * 4];
        *(facc4*)&sumb_p[((size_t)at * B_DIM + bbase + b) * 16 + q * 4] = s;
    }
}

// ---------------------------------------------------------------------------
// Kernel 2: node MLP for both sides, inlined 2-way-split partial reduction.
// a-side: 32 partials (bg x mh); b-side: 64 partials (at).
// ---------------------------------------------------------------------------
__global__ __launch_bounds__(256) void node_kernel(
    const float* __restrict__ na, const float* __restrict__ nb,
    const float* __restrict__ suma_p, const float* __restrict__ sumb_p,
    const float* __restrict__ W1n, const float* __restrict__ b1n,
    const float* __restrict__ W2n, const float* __restrict__ b2n,
    float* __restrict__ out_a, float* __restrict__ out_b)
{
    __shared__ float W1_s[48 * 32];
    __shared__ float W2_s[32 * 32];
    __shared__ float hid_s[8][32];
    __shared__ float sx2[8][32];
    __shared__ float sx_s[8][16];
    int tid = threadIdx.x;
    for (int i = tid; i < 1536; i += 256) W1_s[i] = W1n[i];
    for (int i = tid; i < 1024; i += 256) W2_s[i] = W2n[i];
    int rlocal = tid >> 5;
    int r = blockIdx.x * 8 + rlocal;
    int j = tid & 31;
    int isb = (r >= 1024);
    int rr = isb ? r - 1024 : r;
    {
        const float* P = isb ? sumb_p : suma_p;
        int hn = isb ? 32 : 16;
        int d = j & 15, hf = j >> 4;
        float acc = 0.f;
        for (int t = hf * hn; t < hf * hn + hn; ++t)
            acc += P[(size_t)t * 16384 + rr * 16 + d];
        sx2[rlocal][j] = acc;
    }
    __syncthreads();
    if (j < 16) sx_s[rlocal][j] = sx2[rlocal][j] + sx2[rlocal][j + 16];
    __syncthreads();
    const float* nx = (isb ? nb : na) + rr * 32;
    float acc = b1n[j];
    #pragma unroll
    for (int k = 0; k < 32; ++k) acc += nx[k] * W1_s[k * 32 + j];
    #pragma unroll
    for (int k = 0; k < 16; ++k) acc += sx_s[rlocal][k] * W1_s[(32 + k) * 32 + j];
    hid_s[rlocal][j] = fmaxf(acc, 0.f);
    __syncthreads();
    float acc2 = b2n[j];
    #pragma unroll
    for (int k = 0; k < 32; ++k) acc2 += hid_s[rlocal][k] * W2_s[k * 32 + j];
    (isb ? out_b : out_a)[rr * 32 + j] = fmaxf(acc2, 0.f);
}

extern "C" void kernel_launch(void* const* d_in, const int* in_sizes, int n_in,
                              void* d_out, int out_size, void* d_ws, size_t ws_size,
                              hipStream_t stream)
{
    const float* E   = (const float*)d_in[0];
    const float* na  = (const float*)d_in[1];
    const float* nb  = (const float*)d_in[2];
    const float* W1e = (const float*)d_in[3];
    const float* b1e = (const float*)d_in[4];
    const float* W2e = (const float*)d_in[5];
    const float* b2e = (const float*)d_in[6];
    const float* W1n = (const float*)d_in[7];
    const float* b1n = (const float*)d_in[8];
    const float* W2n = (const float*)d_in[9];
    const float* b2n = (const float*)d_in[10];

    float* out    = (float*)d_out;
    float* el_out = out;
    float* out_a  = out + (size_t)A_DIM * B_DIM * 16;
    float* out_b  = out_a + A_DIM * 32;

    float* ws     = (float*)d_ws;
    float* suma_p = ws;                      // 32 * 16384
    float* sumb_p = ws + 32 * 16384;         // 64 * 16384

    hipLaunchKernelGGL(edge_kernel, dim3(16, 64), dim3(512), 0, stream,
                       E, na, nb, W1e, b1e, W2e, b2e, el_out, suma_p, sumb_p);
    hipLaunchKernelGGL(node_kernel, dim3(256), dim3(256), 0, stream,
                       na, nb, suma_p, sumb_p, W1n, b1n, W2n, b2n, out_a, out_b);
}

// Round 12
// 47.254 us; speedup vs baseline: 1.3609x; 1.1792x over previous
//
#include <hip/hip_runtime.h>

#define A_DIM 1024
#define B_DIM 1024

typedef __attribute__((ext_vector_type(8))) short bfrag8;
typedef __attribute__((ext_vector_type(4))) float facc4;

__device__ __forceinline__ unsigned short f2bf(float f) {
    unsigned u = __float_as_uint(f);
    u = (u + 0x7FFFu + ((u >> 16) & 1u)) >> 16;
    return (unsigned short)u;
}
__device__ __forceinline__ unsigned cvtpk(float lo, float hi) {
    unsigned r;
    asm("v_cvt_pk_bf16_f32 %0, %1, %2" : "=v"(r) : "v"(lo), "v"(hi));
    return r;
}

// ---------------------------------------------------------------------------
// Kernel 1: fused prep + edge MLP via MFMA. EXACTLY R10's verified 2-deep
// register-pinned asm pipeline (56 VGPR, no spill -- the R11 3-deep variant
// spilled pinned async-load targets and faulted), extended to 8 rows/wave so
// the prologue (prep + baseline drain + fill) amortizes over 2x the work.
// Counted s_waitcnt vmcnt = {4,7,7,7,7,7,7,3}: steady-state {7} is R10's
// hardware-verified count (4 asm loads/stage, 3 asm stores/step, in-order
// retirement). sched_barrier(0) after every wait (rule #18).
// Grid (16 bg, 32 at) = 512 blocks x 512 thr (8 waves), 2 blocks/CU.
// Wave w: b-half mh=w&1 (mt tiles 2mh,2mh+1), rows r0 = at*32+(w>>1)*8..+7.
// C/D layout: col = lane&15 (edge), row = (lane>>4)*4 + reg.
// ---------------------------------------------------------------------------
__global__ __launch_bounds__(512, 4) void edge_kernel(
    const float* __restrict__ E, const float* __restrict__ na,
    const float* __restrict__ nb, const float* __restrict__ W1e,
    const float* __restrict__ b1e, const float* __restrict__ W2e,
    const float* __restrict__ b2e, float* __restrict__ el_out,
    float* __restrict__ suma_p, float* __restrict__ sumb_p)
{
    __shared__ __align__(16) float sb[4096];          // 16 KB: prep stage / combine
    __shared__ __align__(16) float ha_s[32 * 16];     // 2 KB
    __shared__ __align__(16) float hb_s[64 * 16];     // 4 KB

    const int tid  = threadIdx.x;
    const int lane = tid & 63;
    const int w    = tid >> 6;          // 0..7
    const int n    = lane & 15;
    const int g    = lane >> 4;
    const int bg   = blockIdx.x;        // 0..15
    const int at   = blockIdx.y;        // 0..31
    const int bbase = bg * 64;
    const int abase = at * 32;
    const int mh   = w & 1;
    const int rg   = w >> 1;            // 0..3
    const int r0   = abase + rg * 8;
    const int mt0  = mh * 2, mt1 = mh * 2 + 1;

    float4 bufA[4], bufB[4];

#define LOADH(BUF, AROW)                                                       \
    {                                                                          \
        const float* p_  = E + ((size_t)(AROW) * B_DIM + bbase) * 32;          \
        const float* p0_ = p_ + (mt0 * 16 + n) * 32 + g * 8;                   \
        const float* p1_ = p_ + (mt1 * 16 + n) * 32 + g * 8;                   \
        asm volatile("global_load_dwordx4 %0, %1, off"                         \
                     : "=v"(BUF[0]) : "v"(p0_) : "memory");                    \
        asm volatile("global_load_dwordx4 %0, %1, off"                         \
                     : "=v"(BUF[1]) : "v"(p0_ + 4) : "memory");                \
        asm volatile("global_load_dwordx4 %0, %1, off"                         \
                     : "=v"(BUF[2]) : "v"(p1_) : "memory");                    \
        asm volatile("global_load_dwordx4 %0, %1, off"                         \
                     : "=v"(BUF[3]) : "v"(p1_ + 4) : "memory");                \
    }

    // ---- prep stage: na tile / nb tile / W1e[32..96) into LDS, coalesced ----
    float* xa_s = sb;                 // 32*32 f32
    float* xb_s = sb + 1024;          // 64*32 f32
    float* wq_s = sb + 1024 + 2048;   // 64*16 f32  (W1e rows 32..95)
    if (tid < 256)
        ((float4*)xa_s)[tid] = ((const float4*)(na + (size_t)abase * 32))[tid];
    ((float4*)xb_s)[tid] = ((const float4*)(nb + (size_t)bbase * 32))[tid];
    if (tid < 256)
        ((float4*)wq_s)[tid] = ((const float4*)(W1e + 32 * 16))[tid];

    // weight fragments (global, L1-hot; complete before the baseline drain)
    bfrag8 w1f, w2f;
    #pragma unroll
    for (int t = 0; t < 8; ++t) {
        w1f[t] = (short)f2bf(W1e[(g * 8 + t) * 16 + n]);
        w2f[t] = (g < 2) ? (short)f2bf(W2e[(g * 8 + t) * 16 + n]) : (short)0;
    }
    facc4 b2f = *(const facc4*)&b2e[g * 4];
    __syncthreads();

    // ---- prep compute: all operands LDS-broadcast ----
    {
        const int r = tid >> 4, d = tid & 15;   // r 0..31
        float acca = b1e[d];
        #pragma unroll
        for (int k = 0; k < 32; ++k)
            acca += xa_s[r * 32 + k] * wq_s[k * 16 + d];
        ha_s[r * 16 + d] = acca;
        float ab0 = 0.f, ab1 = 0.f;
        #pragma unroll
        for (int k = 0; k < 32; ++k) {
            float wv = wq_s[(32 + k) * 16 + d];
            ab0 += xb_s[r * 32 + k] * wv;
            ab1 += xb_s[(r + 32) * 32 + k] * wv;
        }
        hb_s[r * 16 + d] = ab0;
        hb_s[(r + 32) * 16 + d] = ab1;
    }
    __syncthreads();

    facc4 hbF0 = *(const facc4*)&hb_s[(mt0 * 16 + n) * 16 + g * 4];
    facc4 hbF1 = *(const facc4*)&hb_s[(mt1 * 16 + n) * 16 + g * 4];
    facc4 sumb0 = facc4{0.f, 0.f, 0.f, 0.f};
    facc4 sumb1 = facc4{0.f, 0.f, 0.f, 0.f};

#define PVTILE(V0, V1, MT, HBF, SUMB, AROW, HAF)                               \
    {                                                                          \
        union { unsigned u[4]; bfrag8 s; } ef_;                                \
        ef_.u[0] = cvtpk((V0).x, (V0).y); ef_.u[1] = cvtpk((V0).z, (V0).w);    \
        ef_.u[2] = cvtpk((V1).x, (V1).y); ef_.u[3] = cvtpk((V1).z, (V1).w);    \
        facc4 h_ = __builtin_amdgcn_mfma_f32_16x16x32_bf16(                    \
            w1f, ef_.s, (HAF) + (HBF), 0, 0, 0);                               \
        h_.x = fmaxf(h_.x, 0.f); h_.y = fmaxf(h_.y, 0.f);                      \
        h_.z = fmaxf(h_.z, 0.f); h_.w = fmaxf(h_.w, 0.f);                      \
        const int sl_ = (n + g * 32) & 63;                                     \
        const int sh_ = (n + g * 32 + 16) & 63;                                \
        float v0_ = __shfl(h_.x, sl_), v1_ = __shfl(h_.y, sl_);                \
        float v2_ = __shfl(h_.z, sl_), v3_ = __shfl(h_.w, sl_);                \
        float u0_ = __shfl(h_.x, sh_), u1_ = __shfl(h_.y, sh_);                \
        float u2_ = __shfl(h_.z, sh_), u3_ = __shfl(h_.w, sh_);                \
        union { unsigned u[4]; bfrag8 s; } bb_;                                \
        bb_.u[0] = cvtpk(v0_, v1_); bb_.u[1] = cvtpk(v2_, v3_);                \
        bb_.u[2] = cvtpk(u0_, u1_); bb_.u[3] = cvtpk(u2_, u3_);                \
        facc4 e_ = __builtin_amdgcn_mfma_f32_16x16x32_bf16(                    \
            w2f, bb_.s, b2f, 0, 0, 0);                                         \
        e_.x = fmaxf(e_.x, 0.f); e_.y = fmaxf(e_.y, 0.f);                      \
        e_.z = fmaxf(e_.z, 0.f); e_.w = fmaxf(e_.w, 0.f);                      \
        float* op_ = &el_out[((size_t)(AROW) * B_DIM + bbase + (MT) * 16 + n)  \
                             * 16 + g * 4];                                    \
        asm volatile("global_store_dwordx4 %0, %1, off"                        \
                     :: "v"(op_), "v"(e_) : "memory");                         \
        SUMB += e_;                                                            \
        ssum += e_;                                                            \
    }

#define COMPUTE(BUF, AROW, S)                                                  \
    {                                                                          \
        facc4 haf_ = *(const facc4*)&ha_s[(rg * 8 + (S)) * 16 + g * 4];        \
        facc4 ssum = facc4{0.f, 0.f, 0.f, 0.f};                                \
        PVTILE(BUF[0], BUF[1], mt0, hbF0, sumb0, AROW, haf_)                   \
        PVTILE(BUF[2], BUF[3], mt1, hbF1, sumb1, AROW, haf_)                   \
        _Pragma("unroll")                                                      \
        for (int m_ = 1; m_ <= 8; m_ <<= 1) {                                  \
            ssum.x += __shfl_xor(ssum.x, m_);                                  \
            ssum.y += __shfl_xor(ssum.y, m_);                                  \
            ssum.z += __shfl_xor(ssum.z, m_);                                  \
            ssum.w += __shfl_xor(ssum.w, m_);                                  \
        }                                                                      \
        if (n == 0) {                                                          \
            float* sp_ = &suma_p[((size_t)(bg * 2 + mh) * A_DIM + (AROW)) * 16 \
                                 + g * 4];                                     \
            asm volatile("global_store_dwordx4 %0, %1, off"                    \
                         :: "v"(sp_), "v"(ssum) : "memory");                   \
        }                                                                      \
    }

#define WAITV(N)                                                               \
    asm volatile("s_waitcnt vmcnt(" #N ")" ::: "memory");                      \
    __builtin_amdgcn_sched_barrier(0);

    // baseline: no prep vmem outstanding -> counts below are exact
    WAITV(0)

    // 2-deep pinned pipeline, 8 steps (R10-verified steady-state counts):
    // LA LB |4| C0 LA |7| C1 LB |7| C2 LA |7| C3 LB |7| C4 LA |7| C5 LB
    // |7| C6 |3| C7
    LOADH(bufA, r0)
    LOADH(bufB, r0 + 1)
    WAITV(4)
    COMPUTE(bufA, r0, 0)
    LOADH(bufA, r0 + 2)
    WAITV(7)
    COMPUTE(bufB, r0 + 1, 1)
    LOADH(bufB, r0 + 3)
    WAITV(7)
    COMPUTE(bufA, r0 + 2, 2)
    LOADH(bufA, r0 + 4)
    WAITV(7)
    COMPUTE(bufB, r0 + 3, 3)
    LOADH(bufB, r0 + 5)
    WAITV(7)
    COMPUTE(bufA, r0 + 4, 4)
    LOADH(bufA, r0 + 6)
    WAITV(7)
    COMPUTE(bufB, r0 + 5, 5)
    LOADH(bufB, r0 + 7)
    WAITV(7)
    COMPUTE(bufA, r0 + 6, 6)
    WAITV(3)
    COMPUTE(bufB, r0 + 7, 7)

#undef LOADH
#undef PVTILE
#undef COMPUTE
#undef WAITV

    // ---- sumb combine across the 4 waves sharing each b-half ----
    __syncthreads();
    *(facc4*)&sb[((w * 32 + n) * 4 + g) * 4]      = sumb0;
    *(facc4*)&sb[((w * 32 + 16 + n) * 4 + g) * 4] = sumb1;
    __syncthreads();
    if (tid < 256) {
        const int b = tid >> 2, q = tid & 3;
        const int mh2 = b >> 5, rest = b & 31;
        facc4 s = facc4{0.f, 0.f, 0.f, 0.f};
        #pragma unroll
        for (int rg2 = 0; rg2 < 4; ++rg2)
            s += *(const facc4*)&sb[(((rg2 * 2 + mh2) * 32 + rest) * 4 + q) * 4];
        *(facc4*)&sumb_p[((size_t)at * B_DIM + bbase + b) * 16 + q * 4] = s;
    }
}

// ---------------------------------------------------------------------------
// Kernel 2: node MLP for both sides, inlined partial reduction.
// Both sides have 32 partials (split 2x16 across lane halves).
// ---------------------------------------------------------------------------
__global__ __launch_bounds__(256) void node_kernel(
    const float* __restrict__ na, const float* __restrict__ nb,
    const float* __restrict__ suma_p, const float* __restrict__ sumb_p,
    const float* __restrict__ W1n, const float* __restrict__ b1n,
    const float* __restrict__ W2n, const float* __restrict__ b2n,
    float* __restrict__ out_a, float* __restrict__ out_b)
{
    __shared__ float W1_s[48 * 32];
    __shared__ float W2_s[32 * 32];
    __shared__ float hid_s[8][32];
    __shared__ float sx2[8][32];
    __shared__ float sx_s[8][16];
    int tid = threadIdx.x;
    for (int i = tid; i < 1536; i += 256) W1_s[i] = W1n[i];
    for (int i = tid; i < 1024; i += 256) W2_s[i] = W2n[i];
    int rlocal = tid >> 5;
    int r = blockIdx.x * 8 + rlocal;
    int j = tid & 31;
    int isb = (r >= 1024);
    int rr = isb ? r - 1024 : r;
    {
        const float* P = isb ? sumb_p : suma_p;
        int d = j & 15, hf = j >> 4;
        float acc = 0.f;
        #pragma unroll
        for (int t = hf * 16; t < hf * 16 + 16; ++t)
            acc += P[(size_t)t * 16384 + rr * 16 + d];
        sx2[rlocal][j] = acc;
    }
    __syncthreads();
    if (j < 16) sx_s[rlocal][j] = sx2[rlocal][j] + sx2[rlocal][j + 16];
    __syncthreads();
    const float* nx = (isb ? nb : na) + rr * 32;
    float acc = b1n[j];
    #pragma unroll
    for (int k = 0; k < 32; ++k) acc += nx[k] * W1_s[k * 32 + j];
    #pragma unroll
    for (int k = 0; k < 16; ++k) acc += sx_s[rlocal][k] * W1_s[(32 + k) * 32 + j];
    hid_s[rlocal][j] = fmaxf(acc, 0.f);
    __syncthreads();
    float acc2 = b2n[j];
    #pragma unroll
    for (int k = 0; k < 32; ++k) acc2 += hid_s[rlocal][k] * W2_s[k * 32 + j];
    (isb ? out_b : out_a)[rr * 32 + j] = fmaxf(acc2, 0.f);
}

extern "C" void kernel_launch(void* const* d_in, const int* in_sizes, int n_in,
                              void* d_out, int out_size, void* d_ws, size_t ws_size,
                              hipStream_t stream)
{
    const float* E   = (const float*)d_in[0];
    const float* na  = (const float*)d_in[1];
    const float* nb  = (const float*)d_in[2];
    const float* W1e = (const float*)d_in[3];
    const float* b1e = (const float*)d_in[4];
    const float* W2e = (const float*)d_in[5];
    const float* b2e = (const float*)d_in[6];
    const float* W1n = (const float*)d_in[7];
    const float* b1n = (const float*)d_in[8];
    const float* W2n = (const float*)d_in[9];
    const float* b2n = (const float*)d_in[10];

    float* out    = (float*)d_out;
    float* el_out = out;
    float* out_a  = out + (size_t)A_DIM * B_DIM * 16;
    float* out_b  = out_a + A_DIM * 32;

    float* ws     = (float*)d_ws;
    float* suma_p = ws;                      // 32 * 16384
    float* sumb_p = ws + 32 * 16384;         // 32 * 16384

    hipLaunchKernelGGL(edge_kernel, dim3(16, 32), dim3(512), 0, stream,
                       E, na, nb, W1e, b1e, W2e, b2e, el_out, suma_p, sumb_p);
    hipLaunchKernelGGL(node_kernel, dim3(256), dim3(256), 0, stream,
                       na, nb, suma_p, sumb_p, W1n, b1n, W2n, b2n, out_a, out_b);
}